// Round 1
// baseline (568.718 us; speedup 1.0000x reference)
//
#include <hip/hip_runtime.h>
#include <math.h>

#define B_     2
#define L_     768
#define SIN_   1280
#define SOUT_  32
#define DI_    64
#define DST_   16
#define DCONV_ 4
#define DTR_   2

// ---------------- workspace layout (float offsets) ----------------
// xz   : [B*L][128]   off 0        size 196608   (x = [:,0:64], gate = [:,64:128])
// xs   : [B*L][64]    off 196608   size 98304    (post conv+silu x)
// dtf  : [B*L][64]    off 294912   size 98304    (softplus dt)
// dtx  : [B*L][64]    off 393216   size 98304    (dt * xs)
// Bws  : [B*L][16]    off 491520   size 24576
// Cws  : [B*L][16]    off 516096   size 24576
// ysc  : [B*L][64]    off 540672   size 98304    (scan output)
// total 638976 floats = 2.56 MB

// Kernel A: s_prime_pre = s @ s_proj_w.T + b, then xz = u @ in_proj_w.T
// 4 rows per block to amortize weight reads through L2.
__global__ __launch_bounds__(256) void k_sproj(
    const float* __restrict__ s, const float* __restrict__ spw,
    const float* __restrict__ spb, const float* __restrict__ ipw,
    float* __restrict__ xz)
{
    __shared__ float srow[4][SIN_];
    __shared__ float w2[2 * DI_ * SOUT_];   // 128x32 in_proj_w
    __shared__ float u[4][SOUT_];
    const int tid = threadIdx.x;
    const int row0 = blockIdx.x * 4;

    for (int r = 0; r < 4; ++r) {
        const float* src = s + (long)(row0 + r) * SIN_;
        for (int i = tid; i < SIN_; i += 256) srow[r][i] = src[i];
    }
    for (int i = tid; i < 2 * DI_ * SOUT_; i += 256) w2[i] = ipw[i];
    __syncthreads();

    const int f = tid >> 3;      // 0..31
    const int c = tid & 7;       // 0..7
    float p0 = 0.f, p1 = 0.f, p2 = 0.f, p3 = 0.f;
    const float* wrow = spw + (long)f * SIN_;
    for (int k = c; k < SIN_; k += 8) {
        float w = wrow[k];
        p0 += srow[0][k] * w; p1 += srow[1][k] * w;
        p2 += srow[2][k] * w; p3 += srow[3][k] * w;
    }
    #pragma unroll
    for (int m = 1; m <= 4; m <<= 1) {
        p0 += __shfl_xor(p0, m); p1 += __shfl_xor(p1, m);
        p2 += __shfl_xor(p2, m); p3 += __shfl_xor(p3, m);
    }
    if (c == 0) {
        float b = spb[f];
        u[0][f] = p0 + b; u[1][f] = p1 + b;
        u[2][f] = p2 + b; u[3][f] = p3 + b;
    }
    __syncthreads();

    const int j  = tid & 127;    // output channel of xz
    const int rh = tid >> 7;     // 0..1
    #pragma unroll
    for (int rp = 0; rp < 2; ++rp) {
        int r = rp * 2 + rh;
        float acc = 0.f;
        const float* wj = &w2[j * SOUT_];
        #pragma unroll
        for (int k = 0; k < SOUT_; ++k) acc += u[r][k] * wj[k];
        xz[(long)(row0 + r) * 128 + j] = acc;
    }
}

// Kernel C: causal depthwise conv + SiLU + x_proj + dt path; emits scan inputs.
__global__ __launch_bounds__(64) void k_pre(
    const float* __restrict__ xz, const float* __restrict__ convw,
    const float* __restrict__ convb, const float* __restrict__ xpw,
    const float* __restrict__ dtw, const float* __restrict__ dtb,
    float* __restrict__ xs_out, float* __restrict__ dtf,
    float* __restrict__ dtx, float* __restrict__ Bws, float* __restrict__ Cws)
{
    const int row = blockIdx.x;          // b*L + l
    const int b = row / L_;
    const int l = row - b * L_;
    const int d = threadIdx.x;
    __shared__ float xs_l[DI_];
    __shared__ float xdbl[DTR_ + 2 * DST_];   // 34

    float xc = convb[d];
    #pragma unroll
    for (int k = 0; k < DCONV_; ++k) {
        int ls = l + k - (DCONV_ - 1);
        if (ls >= 0) xc += xz[(long)(b * L_ + ls) * 128 + d] * convw[d * DCONV_ + k];
    }
    float xsv = xc / (1.f + expf(-xc));       // SiLU
    xs_l[d] = xsv;
    xs_out[(long)row * DI_ + d] = xsv;
    __syncthreads();

    if (d < DTR_ + 2 * DST_) {
        float acc = 0.f;
        const float* w = xpw + d * DI_;
        #pragma unroll
        for (int k = 0; k < DI_; ++k) acc += xs_l[k] * w[k];
        xdbl[d] = acc;
    }
    __syncthreads();

    if (d < DST_) {
        Bws[(long)row * DST_ + d] = xdbl[DTR_ + d];
        Cws[(long)row * DST_ + d] = xdbl[DTR_ + DST_ + d];
    }
    float dtv = xdbl[0] * dtw[d * 2] + xdbl[1] * dtw[d * 2 + 1] + dtb[d];
    dtv = dtv > 20.f ? dtv : log1pf(expf(dtv));   // softplus
    dtf[(long)row * DI_ + d] = dtv;
    dtx[(long)row * DI_ + d] = dtv * xsv;
}

// Kernel D: sequential selective scan. 32 blocks x 64 threads;
// block = (batch, 4 d-channels), thread = (d_local, n). h kept in a register.
__global__ __launch_bounds__(64) void k_scan(
    const float* __restrict__ dtf, const float* __restrict__ dtx,
    const float* __restrict__ Bws, const float* __restrict__ Cws,
    const float* __restrict__ Alog, float* __restrict__ ysc)
{
    const int b  = blockIdx.x >> 4;
    const int d0 = (blockIdx.x & 15) * 4;
    const int tid = threadIdx.x;
    const int n = tid & 15;
    const int d = d0 + (tid >> 4);
    // A2 = -exp(A_log) * log2(e)  so  exp(dt*A) == exp2f(dt*A2)
    const float A2 = -expf(Alog[d * DST_ + n]) * 1.44269504088896f;
    const long r0 = (long)b * L_;
    float h = 0.f;
    #pragma unroll 4
    for (int l = 0; l < L_; ++l) {
        long row = r0 + l;
        float dt = dtf[row * DI_ + d];
        float dx = dtx[row * DI_ + d];
        float bn = Bws[row * DST_ + n];
        float cn = Cws[row * DST_ + n];
        float e = exp2f(dt * A2);
        h = fmaf(e, h, dx * bn);
        float p = h * cn;
        p += __shfl_xor(p, 1); p += __shfl_xor(p, 2);
        p += __shfl_xor(p, 4); p += __shfl_xor(p, 8);
        if (n == 0) ysc[row * DI_ + d] = p;
    }
}

// Kernel E: y = ysc + xs*D; y *= silu(gate); s_prime = y @ out_proj_w.T
__global__ __launch_bounds__(64) void k_epi(
    const float* __restrict__ ysc, const float* __restrict__ xs,
    const float* __restrict__ xz, const float* __restrict__ Dv,
    const float* __restrict__ opw, float* __restrict__ sp)
{
    const int row = blockIdx.x;
    const int d = threadIdx.x;
    __shared__ float y[DI_];
    float g = xz[(long)row * 128 + DI_ + d];
    float yv = ysc[(long)row * DI_ + d] + xs[(long)row * DI_ + d] * Dv[d];
    yv *= g / (1.f + expf(-g));
    y[d] = yv;
    __syncthreads();
    if (d < SOUT_) {
        float acc = 0.f;
        const float* w = opw + d * DI_;
        #pragma unroll
        for (int k = 0; k < DI_; ++k) acc += y[k] * w[k];
        sp[(long)row * SOUT_ + d] = acc;
    }
}

// Kernel Z: z_prime[b,s,t,f] = z[b,s,t]*zw[f] + zb[f] + sp[b,s,f]*sp[b,t,f]
// One float4 (4 f's) per thread; coalesced 151 MB store stream.
__global__ __launch_bounds__(256) void k_z(
    const float* __restrict__ z, const float* __restrict__ zw,
    const float* __restrict__ zb, const float* __restrict__ sp,
    float* __restrict__ zout)
{
    const int idx = blockIdx.x * 256 + threadIdx.x;   // < B*L*L*8 = 9437184
    const int bs  = idx / 6144;         // b*L + s   (6144 = L*8 float4s)
    const int rem = idx - bs * 6144;
    const int t   = rem >> 3;
    const int f4  = rem & 7;
    const int b   = bs / L_;

    float zval = z[(long)bs * L_ + t];
    float4 w4 = ((const float4*)zw)[f4];
    float4 b4 = ((const float4*)zb)[f4];
    float4 ss = ((const float4*)sp)[bs * 8 + f4];
    float4 st = ((const float4*)sp)[(b * L_ + t) * 8 + f4];
    float4 o;
    o.x = zval * w4.x + b4.x + ss.x * st.x;
    o.y = zval * w4.y + b4.y + ss.y * st.y;
    o.z = zval * w4.z + b4.z + ss.z * st.z;
    o.w = zval * w4.w + b4.w + ss.w * st.w;
    ((float4*)zout)[(long)idx] = o;
}

extern "C" void kernel_launch(void* const* d_in, const int* in_sizes, int n_in,
                              void* d_out, int out_size, void* d_ws, size_t ws_size,
                              hipStream_t stream) {
    const float* s     = (const float*)d_in[0];
    const float* z     = (const float*)d_in[1];
    const float* spw   = (const float*)d_in[2];
    const float* spb   = (const float*)d_in[3];
    const float* zw    = (const float*)d_in[4];
    const float* zb    = (const float*)d_in[5];
    const float* ipw   = (const float*)d_in[6];
    const float* convw = (const float*)d_in[7];
    const float* convb = (const float*)d_in[8];
    const float* xpw   = (const float*)d_in[9];
    const float* dtw   = (const float*)d_in[10];
    const float* dtb   = (const float*)d_in[11];
    const float* Alog  = (const float*)d_in[12];
    const float* Dv    = (const float*)d_in[13];
    const float* opw   = (const float*)d_in[14];

    float* out = (float*)d_out;
    float* ws  = (float*)d_ws;
    float* xz  = ws;
    float* xs  = ws + 196608;
    float* dtf = ws + 294912;
    float* dtx = ws + 393216;
    float* Bws = ws + 491520;
    float* Cws = ws + 516096;
    float* ysc = ws + 540672;

    float* sp   = out;            // s_prime: first 49152 floats of d_out
    float* zout = out + 49152;    // z_prime: remaining 37748736 floats

    k_sproj<<<(B_ * L_) / 4, 256, 0, stream>>>(s, spw, spb, ipw, xz);
    k_pre  <<<B_ * L_, 64, 0, stream>>>(xz, convw, convb, xpw, dtw, dtb,
                                        xs, dtf, dtx, Bws, Cws);
    k_scan <<<B_ * 16, 64, 0, stream>>>(dtf, dtx, Bws, Cws, Alog, ysc);
    k_epi  <<<B_ * L_, 64, 0, stream>>>(ysc, xs, xz, Dv, opw, sp);
    k_z    <<<(B_ * L_ * L_ * 8) / 256, 256, 0, stream>>>(z, zw, zb, sp, zout);
}

// Round 2
// 418.558 us; speedup vs baseline: 1.3588x; 1.3588x over previous
//
#include <hip/hip_runtime.h>
#include <math.h>

#define B_     2
#define L_     768
#define SIN_   1280
#define SOUT_  32
#define DI_    64
#define DST_   16
#define DCONV_ 4
#define DTR_   2

// ---------------- workspace layout (float offsets) ----------------
// xz   : [B*L][128]   off 0        (x = [:,0:64], gate = [:,64:128])
// xs   : [B*L][64]    off 196608
// dtf  : [B*L][64]    off 294912
// dtx  : [B*L][64]    off 393216
// Bws  : [B*L][16]    off 491520
// Cws  : [B*L][16]    off 516096
// ysc  : [B*L][64]    off 540672

// Kernel A: s_prime_pre = s @ s_proj_w.T + b, then xz = u @ in_proj_w.T
__global__ __launch_bounds__(256) void k_sproj(
    const float* __restrict__ s, const float* __restrict__ spw,
    const float* __restrict__ spb, const float* __restrict__ ipw,
    float* __restrict__ xz)
{
    __shared__ float srow[4][SIN_];
    __shared__ float w2[2 * DI_ * SOUT_];   // 128x32 in_proj_w
    __shared__ float u[4][SOUT_];
    const int tid = threadIdx.x;
    const int row0 = blockIdx.x * 4;

    for (int r = 0; r < 4; ++r) {
        const float* src = s + (long)(row0 + r) * SIN_;
        for (int i = tid; i < SIN_; i += 256) srow[r][i] = src[i];
    }
    for (int i = tid; i < 2 * DI_ * SOUT_; i += 256) w2[i] = ipw[i];
    __syncthreads();

    const int f = tid >> 3;      // 0..31
    const int c = tid & 7;       // 0..7
    float p0 = 0.f, p1 = 0.f, p2 = 0.f, p3 = 0.f;
    const float* wrow = spw + (long)f * SIN_;
    for (int k = c; k < SIN_; k += 8) {
        float w = wrow[k];
        p0 += srow[0][k] * w; p1 += srow[1][k] * w;
        p2 += srow[2][k] * w; p3 += srow[3][k] * w;
    }
    #pragma unroll
    for (int m = 1; m <= 4; m <<= 1) {
        p0 += __shfl_xor(p0, m); p1 += __shfl_xor(p1, m);
        p2 += __shfl_xor(p2, m); p3 += __shfl_xor(p3, m);
    }
    if (c == 0) {
        float b = spb[f];
        u[0][f] = p0 + b; u[1][f] = p1 + b;
        u[2][f] = p2 + b; u[3][f] = p3 + b;
    }
    __syncthreads();

    const int j  = tid & 127;    // output channel of xz
    const int rh = tid >> 7;     // 0..1
    #pragma unroll
    for (int rp = 0; rp < 2; ++rp) {
        int r = rp * 2 + rh;
        float acc = 0.f;
        const float* wj = &w2[j * SOUT_];
        #pragma unroll
        for (int k = 0; k < SOUT_; ++k) acc += u[r][k] * wj[k];
        xz[(long)(row0 + r) * 128 + j] = acc;
    }
}

// Kernel C: causal depthwise conv + SiLU + x_proj + dt path; emits scan inputs.
__global__ __launch_bounds__(64) void k_pre(
    const float* __restrict__ xz, const float* __restrict__ convw,
    const float* __restrict__ convb, const float* __restrict__ xpw,
    const float* __restrict__ dtw, const float* __restrict__ dtb,
    float* __restrict__ xs_out, float* __restrict__ dtf,
    float* __restrict__ dtx, float* __restrict__ Bws, float* __restrict__ Cws)
{
    const int row = blockIdx.x;          // b*L + l
    const int b = row / L_;
    const int l = row - b * L_;
    const int d = threadIdx.x;
    __shared__ float xs_l[DI_];
    __shared__ float xdbl[DTR_ + 2 * DST_];   // 34

    float xc = convb[d];
    #pragma unroll
    for (int k = 0; k < DCONV_; ++k) {
        int ls = l + k - (DCONV_ - 1);
        if (ls >= 0) xc += xz[(long)(b * L_ + ls) * 128 + d] * convw[d * DCONV_ + k];
    }
    float xsv = xc / (1.f + expf(-xc));       // SiLU
    xs_l[d] = xsv;
    xs_out[(long)row * DI_ + d] = xsv;
    __syncthreads();

    if (d < DTR_ + 2 * DST_) {
        float acc = 0.f;
        const float* w = xpw + d * DI_;
        #pragma unroll
        for (int k = 0; k < DI_; ++k) acc += xs_l[k] * w[k];
        xdbl[d] = acc;
    }
    __syncthreads();

    if (d < DST_) {
        Bws[(long)row * DST_ + d] = xdbl[DTR_ + d];
        Cws[(long)row * DST_ + d] = xdbl[DTR_ + DST_ + d];
    }
    float dtv = xdbl[0] * dtw[d * 2] + xdbl[1] * dtw[d * 2 + 1] + dtb[d];
    dtv = dtv > 20.f ? dtv : log1pf(expf(dtv));   // softplus
    dtf[(long)row * DI_ + d] = dtv;
    dtx[(long)row * DI_ + d] = dtv * xsv;
}

// Kernel D v2: chunked double-buffered selective scan.
// 8 blocks = (batch, d-group of 16). 256 threads = (16 d_local x 16 n).
// Chunks of TCH timesteps staged to LDS; fetch-to-reg BEFORE the scan loop,
// ds_write AFTER it, so the vmcnt wait lands after the compute (true overlap).
#define TCH 128
__global__ __launch_bounds__(256) void k_scan2(
    const float* __restrict__ dtf, const float* __restrict__ dtx,
    const float* __restrict__ Bws, const float* __restrict__ Cws,
    const float* __restrict__ Alog, float* __restrict__ ysc)
{
    const int b  = blockIdx.x >> 2;
    const int dg = (blockIdx.x & 3) * 16;      // d-group base
    const int tid = threadIdx.x;
    const int n  = tid & 15;
    const int dl = tid >> 4;                   // 0..15
    const int d  = dg + dl;

    __shared__ float sdt[2][TCH][16];
    __shared__ float sdx[2][TCH][16];
    __shared__ float sB [2][TCH][16];
    __shared__ float sC [2][TCH][16];          // 64 KB total

    // A2 = -exp(A_log) * log2(e)  so  exp(dt*A) == exp2f(dt*A2)
    const float A2 = -expf(Alog[d * DST_ + n]) * 1.44269504088896f;
    const long r0 = (long)b * L_;

    float4 r_dt[2], r_dx[2], r_B[2], r_C[2];
    int   r_l[2], r_j[2];

    auto fetch = [&](int c) {
        #pragma unroll
        for (int i = 0; i < 2; ++i) {
            int idx = tid + i * 256;           // 0..511
            int l = idx >> 2, j4 = idx & 3;
            long row = r0 + (long)c * TCH + l;
            r_l[i] = l; r_j[i] = j4;
            r_dt[i] = *(const float4*)&dtf[row * DI_  + dg + j4 * 4];
            r_dx[i] = *(const float4*)&dtx[row * DI_  + dg + j4 * 4];
            r_B[i]  = *(const float4*)&Bws[row * DST_ + j4 * 4];
            r_C[i]  = *(const float4*)&Cws[row * DST_ + j4 * 4];
        }
    };
    auto commit = [&](int buf) {
        #pragma unroll
        for (int i = 0; i < 2; ++i) {
            ((float4*)&sdt[buf][r_l[i]][0])[r_j[i]] = r_dt[i];
            ((float4*)&sdx[buf][r_l[i]][0])[r_j[i]] = r_dx[i];
            ((float4*)&sB [buf][r_l[i]][0])[r_j[i]] = r_B[i];
            ((float4*)&sC [buf][r_l[i]][0])[r_j[i]] = r_C[i];
        }
    };

    const int nch = L_ / TCH;                  // 6
    fetch(0); commit(0);
    __syncthreads();

    float h = 0.f;
    for (int c = 0; c < nch; ++c) {
        if (c + 1 < nch) fetch(c + 1);         // loads in flight during scan
        const int buf = c & 1;
        const long rowbase = r0 + (long)c * TCH;
        #pragma unroll 4
        for (int l = 0; l < TCH; ++l) {
            float dt = sdt[buf][l][dl];
            float dx = sdx[buf][l][dl];
            float bn = sB[buf][l][n];
            float cn = sC[buf][l][n];
            float e = exp2f(dt * A2);
            h = fmaf(e, h, dx * bn);
            float p = h * cn;
            p += __shfl_xor(p, 1); p += __shfl_xor(p, 2);
            p += __shfl_xor(p, 4); p += __shfl_xor(p, 8);
            if (n == 0) ysc[(rowbase + l) * DI_ + d] = p;
        }
        if (c + 1 < nch) commit((c + 1) & 1);  // vmcnt wait lands here
        __syncthreads();
    }
}

// Kernel E: y = ysc + xs*D; y *= silu(gate); s_prime = y @ out_proj_w.T
__global__ __launch_bounds__(64) void k_epi(
    const float* __restrict__ ysc, const float* __restrict__ xs,
    const float* __restrict__ xz, const float* __restrict__ Dv,
    const float* __restrict__ opw, float* __restrict__ sp)
{
    const int row = blockIdx.x;
    const int d = threadIdx.x;
    __shared__ float y[DI_];
    float g = xz[(long)row * 128 + DI_ + d];
    float yv = ysc[(long)row * DI_ + d] + xs[(long)row * DI_ + d] * Dv[d];
    yv *= g / (1.f + expf(-g));
    y[d] = yv;
    __syncthreads();
    if (d < SOUT_) {
        float acc = 0.f;
        const float* w = opw + d * DI_;
        #pragma unroll
        for (int k = 0; k < DI_; ++k) acc += y[k] * w[k];
        sp[(long)row * SOUT_ + d] = acc;
    }
}

// Kernel Z: z_prime[b,s,t,f] = z[b,s,t]*zw[f] + zb[f] + sp[b,s,f]*sp[b,t,f]
__global__ __launch_bounds__(256) void k_z(
    const float* __restrict__ z, const float* __restrict__ zw,
    const float* __restrict__ zb, const float* __restrict__ sp,
    float* __restrict__ zout)
{
    const int idx = blockIdx.x * 256 + threadIdx.x;   // < B*L*L*8 = 9437184
    const int bs  = idx / 6144;         // b*L + s   (6144 = L*8 float4s)
    const int rem = idx - bs * 6144;
    const int t   = rem >> 3;
    const int f4  = rem & 7;
    const int b   = bs / L_;

    float zval = z[(long)bs * L_ + t];
    float4 w4 = ((const float4*)zw)[f4];
    float4 b4 = ((const float4*)zb)[f4];
    float4 ss = ((const float4*)sp)[bs * 8 + f4];
    float4 st = ((const float4*)sp)[(b * L_ + t) * 8 + f4];
    float4 o;
    o.x = zval * w4.x + b4.x + ss.x * st.x;
    o.y = zval * w4.y + b4.y + ss.y * st.y;
    o.z = zval * w4.z + b4.z + ss.z * st.z;
    o.w = zval * w4.w + b4.w + ss.w * st.w;
    ((float4*)zout)[(long)idx] = o;
}

extern "C" void kernel_launch(void* const* d_in, const int* in_sizes, int n_in,
                              void* d_out, int out_size, void* d_ws, size_t ws_size,
                              hipStream_t stream) {
    const float* s     = (const float*)d_in[0];
    const float* z     = (const float*)d_in[1];
    const float* spw   = (const float*)d_in[2];
    const float* spb   = (const float*)d_in[3];
    const float* zw    = (const float*)d_in[4];
    const float* zb    = (const float*)d_in[5];
    const float* ipw   = (const float*)d_in[6];
    const float* convw = (const float*)d_in[7];
    const float* convb = (const float*)d_in[8];
    const float* xpw   = (const float*)d_in[9];
    const float* dtw   = (const float*)d_in[10];
    const float* dtb   = (const float*)d_in[11];
    const float* Alog  = (const float*)d_in[12];
    const float* Dv    = (const float*)d_in[13];
    const float* opw   = (const float*)d_in[14];

    float* out = (float*)d_out;
    float* ws  = (float*)d_ws;
    float* xz  = ws;
    float* xs  = ws + 196608;
    float* dtf = ws + 294912;
    float* dtx = ws + 393216;
    float* Bws = ws + 491520;
    float* Cws = ws + 516096;
    float* ysc = ws + 540672;

    float* sp   = out;            // s_prime: first 49152 floats of d_out
    float* zout = out + 49152;    // z_prime: remaining 37748736 floats

    k_sproj<<<(B_ * L_) / 4, 256, 0, stream>>>(s, spw, spb, ipw, xz);
    k_pre  <<<B_ * L_, 64, 0, stream>>>(xz, convw, convb, xpw, dtw, dtb,
                                        xs, dtf, dtx, Bws, Cws);
    k_scan2<<<B_ * 4, 256, 0, stream>>>(dtf, dtx, Bws, Cws, Alog, ysc);
    k_epi  <<<B_ * L_, 64, 0, stream>>>(ysc, xs, xz, Dv, opw, sp);
    k_z    <<<(B_ * L_ * L_ * 8) / 256, 256, 0, stream>>>(z, zw, zb, sp, zout);
}

// Round 3
// 281.517 us; speedup vs baseline: 2.0202x; 1.4868x over previous
//
#include <hip/hip_runtime.h>
#include <math.h>

#define B_     2
#define L_     768
#define SIN_   1280
#define SOUT_  32
#define DI_    64
#define DST_   16
#define DCONV_ 4
#define DTR_   2
#define NCH    48
#define CH     16

// ---------------- workspace layout (float offsets) ----------------
// xz   : [B*L][128]   off 0        (x = [:,0:64], gate = [:,64:128])
// xs   : [B*L][64]    off 196608
// dtf  : [B*L][64]    off 294912
// dtx  : [B*L][64]    off 393216
// Bws  : [B*L][16]    off 491520
// Cws  : [B*L][16]    off 516096
// ysc  : [B*L][64]    off 540672
// Pst  : [B*NCH][64][16] off 638976   (per-chunk elementwise prod of a)
// Lst  : [B*NCH][64][16] off 737280   (per-chunk local scan end)
// Hst  : [B*NCH][64][16] off 835584   (state at chunk START)
// total 933888 floats = 3.74 MB

// Kernel A: s_prime_pre = s @ s_proj_w.T + b, then xz = u @ in_proj_w.T
__global__ __launch_bounds__(256) void k_sproj(
    const float* __restrict__ s, const float* __restrict__ spw,
    const float* __restrict__ spb, const float* __restrict__ ipw,
    float* __restrict__ xz)
{
    __shared__ float srow[4][SIN_];
    __shared__ float w2[2 * DI_ * SOUT_];   // 128x32 in_proj_w
    __shared__ float u[4][SOUT_];
    const int tid = threadIdx.x;
    const int row0 = blockIdx.x * 4;

    for (int r = 0; r < 4; ++r) {
        const float* src = s + (long)(row0 + r) * SIN_;
        for (int i = tid; i < SIN_; i += 256) srow[r][i] = src[i];
    }
    for (int i = tid; i < 2 * DI_ * SOUT_; i += 256) w2[i] = ipw[i];
    __syncthreads();

    const int f = tid >> 3;      // 0..31
    const int c = tid & 7;       // 0..7
    float p0 = 0.f, p1 = 0.f, p2 = 0.f, p3 = 0.f;
    const float* wrow = spw + (long)f * SIN_;
    for (int k = c; k < SIN_; k += 8) {
        float w = wrow[k];
        p0 += srow[0][k] * w; p1 += srow[1][k] * w;
        p2 += srow[2][k] * w; p3 += srow[3][k] * w;
    }
    #pragma unroll
    for (int m = 1; m <= 4; m <<= 1) {
        p0 += __shfl_xor(p0, m); p1 += __shfl_xor(p1, m);
        p2 += __shfl_xor(p2, m); p3 += __shfl_xor(p3, m);
    }
    if (c == 0) {
        float b = spb[f];
        u[0][f] = p0 + b; u[1][f] = p1 + b;
        u[2][f] = p2 + b; u[3][f] = p3 + b;
    }
    __syncthreads();

    const int j  = tid & 127;    // output channel of xz
    const int rh = tid >> 7;     // 0..1
    #pragma unroll
    for (int rp = 0; rp < 2; ++rp) {
        int r = rp * 2 + rh;
        float acc = 0.f;
        const float* wj = &w2[j * SOUT_];
        #pragma unroll
        for (int k = 0; k < SOUT_; ++k) acc += u[r][k] * wj[k];
        xz[(long)(row0 + r) * 128 + j] = acc;
    }
}

// Kernel C v2: conv + SiLU + x_proj + dt path. 4 rows per 256-thread block,
// weights staged (transposed -> conflict-free) in LDS.
__global__ __launch_bounds__(256) void k_pre(
    const float* __restrict__ xz, const float* __restrict__ convw,
    const float* __restrict__ convb, const float* __restrict__ xpw,
    const float* __restrict__ dtw, const float* __restrict__ dtb,
    float* __restrict__ xs_out, float* __restrict__ dtf,
    float* __restrict__ dtx, float* __restrict__ Bws, float* __restrict__ Cws)
{
    const int row0 = blockIdx.x * 4;
    const int tid = threadIdx.x;
    const int r = tid >> 6, d = tid & 63;
    const int row = row0 + r;                  // block never crosses batch (192 blocks/batch)
    const int b = row / L_, l = row - b * L_;
    __shared__ float sxpw[64][34];             // x_proj_w transposed
    __shared__ float sdtw[128];
    __shared__ float sxs[4][DI_];
    __shared__ float sxd[4][34];

    for (int i = tid; i < 34 * 64; i += 256) {
        int j = i >> 6, k = i & 63;
        sxpw[k][j] = xpw[i];
    }
    if (tid < 128) sdtw[tid] = dtw[tid];

    float xc = convb[d];
    #pragma unroll
    for (int k = 0; k < DCONV_; ++k) {
        int ls = l + k - (DCONV_ - 1);
        if (ls >= 0) xc = fmaf(xz[(long)(b * L_ + ls) * 128 + d], convw[d * 4 + k], xc);
    }
    float xsv = xc / (1.f + expf(-xc));        // SiLU
    sxs[r][d] = xsv;
    xs_out[(long)row * DI_ + d] = xsv;
    __syncthreads();

    if (d < DTR_ + 2 * DST_) {
        float acc = 0.f;
        #pragma unroll
        for (int k = 0; k < 64; ++k) acc = fmaf(sxs[r][k], sxpw[k][d], acc);
        sxd[r][d] = acc;
    }
    __syncthreads();

    if (d < DST_) {
        Bws[(long)row * DST_ + d] = sxd[r][DTR_ + d];
        Cws[(long)row * DST_ + d] = sxd[r][DTR_ + DST_ + d];
    }
    float dtv = fmaf(sxd[r][0], sdtw[d * 2], fmaf(sxd[r][1], sdtw[d * 2 + 1], dtb[d]));
    dtv = dtv > 20.f ? dtv : log1pf(expf(dtv));   // softplus
    dtf[(long)row * DI_ + d] = dtv;
    dtx[(long)row * DI_ + d] = dtv * xsv;
}

// ---- chunked associative scan: h_t = a_t h_{t-1} + u_t is linear in h ----
// Pass 1: per (b,chunk), thread=d owns h[16n] in regs. Emit P=prod(a), L=local end.
__global__ __launch_bounds__(64) void k_scan_p1(
    const float* __restrict__ dtf, const float* __restrict__ dtx,
    const float* __restrict__ Bws, const float* __restrict__ Alog,
    float* __restrict__ Pst, float* __restrict__ Lst)
{
    const int bc = blockIdx.x;                 // b*NCH + c
    const int b = bc / NCH, c = bc - b * NCH;
    const int d = threadIdx.x;
    __shared__ float sB[CH * 16];
    const long base = (long)b * L_ + c * CH;
    ((float4*)sB)[d] = ((const float4*)(Bws + base * DST_))[d];   // 256 contiguous floats

    float A2[DST_], P[DST_], hl[DST_];
    #pragma unroll
    for (int n = 0; n < DST_; ++n) {
        A2[n] = -expf(Alog[d * DST_ + n]) * 1.44269504088896f;
        P[n] = 1.f; hl[n] = 0.f;
    }
    __syncthreads();

    #pragma unroll
    for (int l = 0; l < CH; ++l) {
        float dt = dtf[(base + l) * DI_ + d];
        float dx = dtx[(base + l) * DI_ + d];
        #pragma unroll
        for (int n = 0; n < DST_; ++n) {
            float a = exp2f(dt * A2[n]);
            P[n] *= a;
            hl[n] = fmaf(a, hl[n], dx * sB[l * 16 + n]);
        }
    }
    float4* Pp = (float4*)(Pst + ((long)bc * 64 + d) * 16);
    float4* Lp = (float4*)(Lst + ((long)bc * 64 + d) * 16);
    #pragma unroll
    for (int q = 0; q < 4; ++q) {
        Pp[q] = ((float4*)P)[q];
        Lp[q] = ((float4*)hl)[q];
    }
}

// Pass 2: carry combine over chunks. 2048 independent (b,d,n) chains, 48 steps.
// Stores state at chunk START.
__global__ __launch_bounds__(256) void k_scan_p2(
    const float* __restrict__ Pst, const float* __restrict__ Lst,
    float* __restrict__ Hst)
{
    const int idx = blockIdx.x * 256 + threadIdx.x;   // 0..2047
    const int b = idx >> 10, e = idx & 1023;
    float H = 0.f;
    #pragma unroll 8
    for (int c = 0; c < NCH; ++c) {
        long o = ((long)(b * NCH + c)) * 1024 + e;
        Hst[o] = H;
        H = fmaf(Pst[o], H, Lst[o]);
    }
}

// Pass 3: re-run local scan from true chunk-start state; y = sum_n h*C is a
// per-thread register dot — zero cross-lane ops.
__global__ __launch_bounds__(64) void k_scan_p3(
    const float* __restrict__ dtf, const float* __restrict__ dtx,
    const float* __restrict__ Bws, const float* __restrict__ Cws,
    const float* __restrict__ Alog, const float* __restrict__ Hst,
    float* __restrict__ ysc)
{
    const int bc = blockIdx.x;
    const int b = bc / NCH, c = bc - b * NCH;
    const int d = threadIdx.x;
    __shared__ float sB[CH * 16], sC[CH * 16];
    const long base = (long)b * L_ + c * CH;
    ((float4*)sB)[d] = ((const float4*)(Bws + base * DST_))[d];
    ((float4*)sC)[d] = ((const float4*)(Cws + base * DST_))[d];

    float A2[DST_], h[DST_];
    #pragma unroll
    for (int n = 0; n < DST_; ++n)
        A2[n] = -expf(Alog[d * DST_ + n]) * 1.44269504088896f;
    const float4* Hp = (const float4*)(Hst + ((long)bc * 64 + d) * 16);
    #pragma unroll
    for (int q = 0; q < 4; ++q) ((float4*)h)[q] = Hp[q];
    __syncthreads();

    #pragma unroll
    for (int l = 0; l < CH; ++l) {
        float dt = dtf[(base + l) * DI_ + d];
        float dx = dtx[(base + l) * DI_ + d];
        float y = 0.f;
        #pragma unroll
        for (int n = 0; n < DST_; ++n) {
            float a = exp2f(dt * A2[n]);
            h[n] = fmaf(a, h[n], dx * sB[l * 16 + n]);
            y = fmaf(h[n], sC[l * 16 + n], y);
        }
        ysc[(base + l) * DI_ + d] = y;
    }
}

// Kernel E v2: y = ysc + xs*D; y *= silu(gate); s_prime = y @ out_proj_w.T
// 4 rows per 256-thread block, opw staged transposed in LDS.
__global__ __launch_bounds__(256) void k_epi(
    const float* __restrict__ ysc, const float* __restrict__ xs,
    const float* __restrict__ xz, const float* __restrict__ Dv,
    const float* __restrict__ opw, float* __restrict__ sp)
{
    const int row0 = blockIdx.x * 4;
    const int tid = threadIdx.x;
    const int r = tid >> 6, d = tid & 63;
    const int row = row0 + r;
    __shared__ float sy[4][DI_];
    __shared__ float sw[64][SOUT_];            // opw transposed

    for (int i = tid; i < SOUT_ * DI_; i += 256) {
        int f = i >> 6, k = i & 63;
        sw[k][f] = opw[i];
    }
    float g = xz[(long)row * 128 + DI_ + d];
    float yv = fmaf(xs[(long)row * DI_ + d], Dv[d], ysc[(long)row * DI_ + d]);
    yv *= g / (1.f + expf(-g));
    sy[r][d] = yv;
    __syncthreads();

    if (d < SOUT_) {
        float acc = 0.f;
        #pragma unroll
        for (int k = 0; k < DI_; ++k) acc = fmaf(sy[r][k], sw[k][d], acc);
        sp[(long)row * SOUT_ + d] = acc;
    }
}

// Kernel Z: z_prime[b,s,t,f] = z[b,s,t]*zw[f] + zb[f] + sp[b,s,f]*sp[b,t,f]
__global__ __launch_bounds__(256) void k_z(
    const float* __restrict__ z, const float* __restrict__ zw,
    const float* __restrict__ zb, const float* __restrict__ sp,
    float* __restrict__ zout)
{
    const int idx = blockIdx.x * 256 + threadIdx.x;   // < B*L*L*8 = 9437184
    const int bs  = idx / 6144;         // b*L + s   (6144 = L*8 float4s)
    const int rem = idx - bs * 6144;
    const int t   = rem >> 3;
    const int f4  = rem & 7;
    const int b   = bs / L_;

    float zval = z[(long)bs * L_ + t];
    float4 w4 = ((const float4*)zw)[f4];
    float4 b4 = ((const float4*)zb)[f4];
    float4 ss = ((const float4*)sp)[bs * 8 + f4];
    float4 st = ((const float4*)sp)[(b * L_ + t) * 8 + f4];
    float4 o;
    o.x = zval * w4.x + b4.x + ss.x * st.x;
    o.y = zval * w4.y + b4.y + ss.y * st.y;
    o.z = zval * w4.z + b4.z + ss.z * st.z;
    o.w = zval * w4.w + b4.w + ss.w * st.w;
    ((float4*)zout)[(long)idx] = o;
}

extern "C" void kernel_launch(void* const* d_in, const int* in_sizes, int n_in,
                              void* d_out, int out_size, void* d_ws, size_t ws_size,
                              hipStream_t stream) {
    const float* s     = (const float*)d_in[0];
    const float* z     = (const float*)d_in[1];
    const float* spw   = (const float*)d_in[2];
    const float* spb   = (const float*)d_in[3];
    const float* zw    = (const float*)d_in[4];
    const float* zb    = (const float*)d_in[5];
    const float* ipw   = (const float*)d_in[6];
    const float* convw = (const float*)d_in[7];
    const float* convb = (const float*)d_in[8];
    const float* xpw   = (const float*)d_in[9];
    const float* dtw   = (const float*)d_in[10];
    const float* dtb   = (const float*)d_in[11];
    const float* Alog  = (const float*)d_in[12];
    const float* Dv    = (const float*)d_in[13];
    const float* opw   = (const float*)d_in[14];

    float* out = (float*)d_out;
    float* ws  = (float*)d_ws;
    float* xz  = ws;
    float* xs  = ws + 196608;
    float* dtf = ws + 294912;
    float* dtx = ws + 393216;
    float* Bws = ws + 491520;
    float* Cws = ws + 516096;
    float* ysc = ws + 540672;
    float* Pst = ws + 638976;
    float* Lst = ws + 737280;
    float* Hst = ws + 835584;

    float* sp   = out;            // s_prime: first 49152 floats of d_out
    float* zout = out + 49152;    // z_prime: remaining 37748736 floats

    k_sproj  <<<(B_ * L_) / 4, 256, 0, stream>>>(s, spw, spb, ipw, xz);
    k_pre    <<<(B_ * L_) / 4, 256, 0, stream>>>(xz, convw, convb, xpw, dtw, dtb,
                                                 xs, dtf, dtx, Bws, Cws);
    k_scan_p1<<<B_ * NCH, 64, 0, stream>>>(dtf, dtx, Bws, Alog, Pst, Lst);
    k_scan_p2<<<8, 256, 0, stream>>>(Pst, Lst, Hst);
    k_scan_p3<<<B_ * NCH, 64, 0, stream>>>(dtf, dtx, Bws, Cws, Alog, Hst, ysc);
    k_epi    <<<(B_ * L_) / 4, 256, 0, stream>>>(ysc, xs, xz, Dv, opw, sp);
    k_z      <<<(B_ * L_ * L_ * 8) / 256, 256, 0, stream>>>(z, zw, zb, sp, zout);
}